// Round 1
// baseline (327.288 us; speedup 1.0000x reference)
//
#include <hip/hip_runtime.h>
#include <math.h>

// Fused: bilinear-interp (2 grids) -> MLP 6->64->64->1 (leakyReLU, sigmoid).
// Round 0 baseline: pure fp32 VALU, weights in LDS (broadcast reads),
// 2 points per thread to amortize LDS weight reads over 2x FMAs.

#define NTHREADS 256
#define PPT 2  // points per thread

__device__ __forceinline__ void bilerp3(const float* __restrict__ g,
                                        float px, float py, float* f) {
    // grid is (256, 256, 3); H = W = 255; coords in [0,1)
    float fx = px * 255.0f;
    float fy = py * 255.0f;
    int x0 = (int)fx;          // truncation (fx >= 0) matches astype(int32)
    int y0 = (int)fy;
    float xf = fx - floorf(fx);  // jnp.mod(fx, 1.0) for fx >= 0
    float yf = fy - floorf(fy);
    int x1 = min(x0 + 1, 255);
    int y1 = min(y0 + 1, 255);
    const float* r00 = g + (y0 * 256 + x0) * 3;  // tl
    const float* r01 = g + (y0 * 256 + x1) * 3;  // tr
    const float* r10 = g + (y1 * 256 + x0) * 3;  // bl
    const float* r11 = g + (y1 * 256 + x1) * 3;  // br
#pragma unroll
    for (int c = 0; c < 3; ++c) {
        float tl = r00[c], tr = r01[c], bl = r10[c], br = r11[c];
        float top = fmaf(xf, tr - tl, tl);  // (1-xf)*tl + xf*tr
        float bot = fmaf(xf, br - bl, bl);
        f[c] = fmaf(yf, bot - top, top);
    }
}

__global__ __launch_bounds__(NTHREADS) void mlp_fused_kernel(
    const float* __restrict__ pos, const float* __restrict__ dir,
    const float* __restrict__ pos_grid, const float* __restrict__ dir_grid,
    const float* __restrict__ W1, const float* __restrict__ b1,
    const float* __restrict__ W2, const float* __restrict__ b2,
    const float* __restrict__ W3, const float* __restrict__ b3,
    float* __restrict__ out, int n_half) {
    __shared__ float sW1[64 * 6];
    __shared__ float sb1[64];
    __shared__ float sW2[64 * 64];
    __shared__ float sb2[64];
    __shared__ float sW3[64];
    __shared__ float sb3;

    const int t = threadIdx.x;
    for (int i = t; i < 64 * 6; i += NTHREADS) sW1[i] = W1[i];
    for (int i = t; i < 64 * 64; i += NTHREADS) sW2[i] = W2[i];
    if (t < 64) {
        sb1[t] = b1[t];
        sb2[t] = b2[t];
        sW3[t] = W3[t];
    }
    if (t == 0) sb3 = b3[0];
    __syncthreads();

    const int tid = blockIdx.x * NTHREADS + t;
    if (tid >= n_half) return;

    // ---- interpolation: 6 features per point ----
    float feat[PPT][6];
#pragma unroll
    for (int p = 0; p < PPT; ++p) {
        int idx = tid + p * n_half;
        float2 pp = ((const float2*)pos)[idx];
        float2 dd = ((const float2*)dir)[idx];
        bilerp3(pos_grid, pp.x, pp.y, &feat[p][0]);
        bilerp3(dir_grid, dd.x, dd.y, &feat[p][3]);
    }

    // ---- layer 1: 6 -> 64, leaky relu ----
    float h1[PPT][64];
#pragma unroll
    for (int o = 0; o < 64; ++o) {
        float w[6];
#pragma unroll
        for (int k = 0; k < 6; ++k) w[k] = sW1[o * 6 + k];
        float bb = sb1[o];
#pragma unroll
        for (int p = 0; p < PPT; ++p) {
            float a = bb;
#pragma unroll
            for (int k = 0; k < 6; ++k) a = fmaf(feat[p][k], w[k], a);
            h1[p][o] = fmaxf(a, 0.01f * a);  // leaky relu
        }
    }

    // ---- layer 2 (64 -> 64, leaky relu) fused with layer 3 (64 -> 1) ----
    float acc3[PPT];
#pragma unroll
    for (int p = 0; p < PPT; ++p) acc3[p] = sb3;

#pragma unroll 2
    for (int o = 0; o < 64; ++o) {
        float a[PPT];
#pragma unroll
        for (int p = 0; p < PPT; ++p) a[p] = sb2[o];
        const float4* w4 = (const float4*)(sW2 + o * 64);
        float w3o = sW3[o];
#pragma unroll
        for (int k4 = 0; k4 < 16; ++k4) {
            float4 w = w4[k4];
#pragma unroll
            for (int p = 0; p < PPT; ++p) {
                a[p] = fmaf(h1[p][4 * k4 + 0], w.x, a[p]);
                a[p] = fmaf(h1[p][4 * k4 + 1], w.y, a[p]);
                a[p] = fmaf(h1[p][4 * k4 + 2], w.z, a[p]);
                a[p] = fmaf(h1[p][4 * k4 + 3], w.w, a[p]);
            }
        }
#pragma unroll
        for (int p = 0; p < PPT; ++p) {
            float z = fmaxf(a[p], 0.01f * a[p]);
            acc3[p] = fmaf(z, w3o, acc3[p]);
        }
    }

    // ---- sigmoid + store ----
#pragma unroll
    for (int p = 0; p < PPT; ++p) {
        out[tid + p * n_half] = 1.0f / (1.0f + expf(-acc3[p]));
    }
}

extern "C" void kernel_launch(void* const* d_in, const int* in_sizes, int n_in,
                              void* d_out, int out_size, void* d_ws,
                              size_t ws_size, hipStream_t stream) {
    const float* pos = (const float*)d_in[0];
    const float* dir = (const float*)d_in[1];
    const float* pos_grid = (const float*)d_in[2];
    const float* dir_grid = (const float*)d_in[3];
    const float* W1 = (const float*)d_in[4];
    const float* b1 = (const float*)d_in[5];
    const float* W2 = (const float*)d_in[6];
    const float* b2 = (const float*)d_in[7];
    const float* W3 = (const float*)d_in[8];
    const float* b3 = (const float*)d_in[9];
    float* out = (float*)d_out;

    const int n = in_sizes[0] / 2;  // number of points (pos is (N,2))
    const int n_half = n / 2;       // PPT == 2: thread tid does {tid, tid+n_half}
    const int blocks = (n_half + NTHREADS - 1) / NTHREADS;

    mlp_fused_kernel<<<blocks, NTHREADS, 0, stream>>>(
        pos, dir, pos_grid, dir_grid, W1, b1, W2, b2, W3, b3, out, n_half);
}

// Round 2
// 226.147 us; speedup vs baseline: 1.4472x; 1.4472x over previous
//
#include <hip/hip_runtime.h>
#include <hip/hip_bf16.h>
#include <math.h>

// R2: full-MFMA pipeline.
//   phase 1: lane=point, bilinear interp -> 6 feats (+1.0 bias lane) -> bf16 -> LDS A1
//   phase 2: layer1 = MFMA 16x16x32 (K padded 6+bias -> 32), B1 frags in VGPRs (bias folded)
//   phase 3: leaky -> bf16 -> LDS A2 (C-layout -> A-layout transpose via ds_write_b16)
//   phase 4: layer2 = MFMA (K=64, 2 K-tiles), B2 frags in VGPRs
//   phase 5: +b2, leaky, dot W3 partial per lane, 16-lane butterfly, sigmoid, store
//
// Wave owns 64 points/batch, NB batches/wave. Block = 4 waves, LDS 57344 B -> 2 blocks/CU.

#define NTHREADS 256
#define NB 4  // 64-point batches per wave

typedef __attribute__((ext_vector_type(8))) short bf16x8;   // 8 bf16 = 4 VGPRs
typedef __attribute__((ext_vector_type(4))) float f32x4;

// per-wave LDS (in shorts): A1 = 64 rows x 40 (32 k + pad, 80 B rows, 16B-aligned)
//                           A2 = 64 rows x 72 (64 k + pad, 144 B rows, 16B-aligned)
#define A1_STRIDE 40
#define A2_STRIDE 72
#define WAVE_LDS (64 * A1_STRIDE + 64 * A2_STRIDE)  // 7168 shorts = 14336 B

static __device__ __forceinline__ short f2bf(float f) {
    __hip_bfloat16 h = __float2bfloat16(f);  // RNE
    return __builtin_bit_cast(short, h);
}

static __device__ __forceinline__ void bilerp3(const float* __restrict__ g,
                                               float px, float py, float* f) {
    float fx = px * 255.0f;
    float fy = py * 255.0f;
    int x0 = (int)fx;            // trunc, fx >= 0
    int y0 = (int)fy;
    float xf = fx - floorf(fx);  // jnp.mod(fx, 1.0), fx >= 0
    float yf = fy - floorf(fy);
    int x1 = min(x0 + 1, 255);
    int y1 = min(y0 + 1, 255);
    const float* r00 = g + (y0 * 256 + x0) * 3;
    const float* r01 = g + (y0 * 256 + x1) * 3;
    const float* r10 = g + (y1 * 256 + x0) * 3;
    const float* r11 = g + (y1 * 256 + x1) * 3;
#pragma unroll
    for (int ch = 0; ch < 3; ++ch) {
        float tl = r00[ch], tr = r01[ch], bl = r10[ch], br = r11[ch];
        float top = fmaf(xf, tr - tl, tl);
        float bot = fmaf(xf, br - bl, bl);
        f[ch] = fmaf(yf, bot - top, top);
    }
}

__global__ __launch_bounds__(NTHREADS, 2) void mlp_mfma_kernel(
    const float* __restrict__ pos, const float* __restrict__ dir,
    const float* __restrict__ pos_grid, const float* __restrict__ dir_grid,
    const float* __restrict__ W1, const float* __restrict__ b1,
    const float* __restrict__ W2, const float* __restrict__ b2,
    const float* __restrict__ W3, const float* __restrict__ b3,
    float* __restrict__ out) {
    __shared__ short lds_all[4 * WAVE_LDS];  // 57344 B

    const int w = threadIdx.x >> 6;
    const int lane = threadIdx.x & 63;
    const int c = lane & 15;   // column: MFMA C/D col, A/B n-or-m index
    const int q = lane >> 4;   // quad: selects k-octet (A/B) or row group (C/D)

    short* A1 = lds_all + w * WAVE_LDS;
    short* A2 = A1 + 64 * A1_STRIDE;

    // ---- one-time: B fragments in VGPRs (weights stay resident; zero per-point traffic)
    // B1[k][n]: k<6 -> W1[n][k]; k==6 -> b1[n] (bias row, pairs with A k=6 == 1.0); else 0
    bf16x8 B1[4];
#pragma unroll
    for (int nt = 0; nt < 4; ++nt) {
        int n = nt * 16 + c;
        bf16x8 t;
#pragma unroll
        for (int j = 0; j < 8; ++j) {
            int k = q * 8 + j;
            float wv = 0.0f;
            if (k < 6) wv = W1[n * 6 + k];
            else if (k == 6) wv = b1[n];
            t[j] = f2bf(wv);
        }
        B1[nt] = t;
    }
    // B2[k][n] = W2[n][k], K = 64 -> 2 K-tiles
    bf16x8 B2[2][4];
#pragma unroll
    for (int kt = 0; kt < 2; ++kt)
#pragma unroll
        for (int nt = 0; nt < 4; ++nt) {
            int n = nt * 16 + c;
            int k0 = kt * 32 + q * 8;
            bf16x8 t;
#pragma unroll
            for (int j = 0; j < 8; ++j) t[j] = f2bf(W2[n * 64 + k0 + j]);
            B2[kt][nt] = t;
        }
    // per-lane epilogue scalars (n = nt*16 + c)
    float b2v[4], w3v[4];
#pragma unroll
    for (int nt = 0; nt < 4; ++nt) {
        b2v[nt] = b2[nt * 16 + c];
        w3v[nt] = W3[nt * 16 + c];
    }
    const float b3s = b3[0];

    // ---- one-time: zero A1 rows, shorts 8..39 (k = 8..31 must read as 0 + pad)
    {
        const bf16x8 z8 = {0, 0, 0, 0, 0, 0, 0, 0};
        short* row = A1 + lane * A1_STRIDE + 8;
#pragma unroll
        for (int i = 0; i < 32; i += 8) *(bf16x8*)(row + i) = z8;
    }
    __syncthreads();

    const long wave_global = (long)blockIdx.x * 4 + w;
    const long base0 = wave_global * (64L * NB);
    const f32x4 zacc = {0.f, 0.f, 0.f, 0.f};

    for (int ib = 0; ib < NB; ++ib) {
        const long base = base0 + ib * 64;
        __syncthreads();  // WAR: prev iter's A1/A2 reads vs this iter's writes

        // ---- phase 1: interp (lane = point), stage A1 fragment row
        float2 pp = ((const float2*)pos)[base + lane];
        float2 dd = ((const float2*)dir)[base + lane];
        float feat[6];
        bilerp3(pos_grid, pp.x, pp.y, feat);
        bilerp3(dir_grid, dd.x, dd.y, feat + 3);
        bf16x8 a1w;
#pragma unroll
        for (int j = 0; j < 6; ++j) a1w[j] = f2bf(feat[j]);
        a1w[6] = f2bf(1.0f);  // bias lane
        a1w[7] = 0;
        *(bf16x8*)(A1 + lane * A1_STRIDE) = a1w;
        __syncthreads();

        // ---- phase 2: layer 1 MFMA (4 M-tiles x 4 N-tiles, 1 K-tile)
        bf16x8 afr[4];
#pragma unroll
        for (int mt = 0; mt < 4; ++mt)
            afr[mt] = *(const bf16x8*)(A1 + (mt * 16 + c) * A1_STRIDE + q * 8);
        f32x4 acc1[4][4];
#pragma unroll
        for (int mt = 0; mt < 4; ++mt)
#pragma unroll
            for (int nt = 0; nt < 4; ++nt)
                acc1[mt][nt] = __builtin_amdgcn_mfma_f32_16x16x32_bf16(
                    afr[mt], B1[nt], zacc, 0, 0, 0);

        // ---- phase 3: leaky + C-layout -> A-layout transpose into A2[m][k]
        // lane holds D[m = mt*16 + q*4 + r][n = nt*16 + c]; n is next layer's k
#pragma unroll
        for (int mt = 0; mt < 4; ++mt)
#pragma unroll
            for (int nt = 0; nt < 4; ++nt) {
                int k2 = nt * 16 + c;
                int mb = mt * 16 + q * 4;
#pragma unroll
                for (int r = 0; r < 4; ++r) {
                    float x = acc1[mt][nt][r];
                    x = fmaxf(x, 0.01f * x);
                    A2[(mb + r) * A2_STRIDE + k2] = f2bf(x);
                }
            }
        __syncthreads();

        // ---- phase 4: layer 2 MFMA (4 M-tiles x 4 N-tiles x 2 K-tiles)
        f32x4 acc2[4][4];
#pragma unroll
        for (int mt = 0; mt < 4; ++mt) {
            const short* rowp = A2 + (mt * 16 + c) * A2_STRIDE + q * 8;
            bf16x8 a0 = *(const bf16x8*)(rowp);
            bf16x8 a1_ = *(const bf16x8*)(rowp + 32);
#pragma unroll
            for (int nt = 0; nt < 4; ++nt) {
                f32x4 t = __builtin_amdgcn_mfma_f32_16x16x32_bf16(
                    a0, B2[0][nt], zacc, 0, 0, 0);
                acc2[mt][nt] = __builtin_amdgcn_mfma_f32_16x16x32_bf16(
                    a1_, B2[1][nt], t, 0, 0, 0);
            }
        }

        // ---- phase 5: +b2, leaky, dot W3, 16-lane butterfly, sigmoid, store
        float s[4][4];
#pragma unroll
        for (int mt = 0; mt < 4; ++mt)
#pragma unroll
            for (int r = 0; r < 4; ++r) {
                float t = 0.0f;
#pragma unroll
                for (int nt = 0; nt < 4; ++nt) {
                    float x = acc2[mt][nt][r] + b2v[nt];
                    x = fmaxf(x, 0.01f * x);
                    t = fmaf(x, w3v[nt], t);
                }
                t += __shfl_xor(t, 1, 64);
                t += __shfl_xor(t, 2, 64);
                t += __shfl_xor(t, 4, 64);
                t += __shfl_xor(t, 8, 64);
                s[mt][r] = t;  // full sum for point mt*16 + q*4 + r, in all 16 lanes of quad
            }
        // lane (c,q) emits point p = (c>>2)*16 + q*4 + (c&3): select s[c>>2][c&3]
        float m_[4];
#pragma unroll
        for (int r = 0; r < 4; ++r) {
            float a_ = (c & 4) ? s[1][r] : s[0][r];
            float b_ = (c & 4) ? s[3][r] : s[2][r];
            m_[r] = (c & 8) ? b_ : a_;
        }
        float x0 = (c & 1) ? m_[1] : m_[0];
        float x1 = (c & 1) ? m_[3] : m_[2];
        float v = (c & 2) ? x1 : x0;
        v += b3s;
        v = 1.0f / (1.0f + expf(-v));
        int p = (c >> 2) * 16 + q * 4 + (c & 3);
        out[base + p] = v;
    }
}

extern "C" void kernel_launch(void* const* d_in, const int* in_sizes, int n_in,
                              void* d_out, int out_size, void* d_ws,
                              size_t ws_size, hipStream_t stream) {
    const float* pos = (const float*)d_in[0];
    const float* dir = (const float*)d_in[1];
    const float* pos_grid = (const float*)d_in[2];
    const float* dir_grid = (const float*)d_in[3];
    const float* W1 = (const float*)d_in[4];
    const float* b1 = (const float*)d_in[5];
    const float* W2 = (const float*)d_in[6];
    const float* b2 = (const float*)d_in[7];
    const float* W3 = (const float*)d_in[8];
    const float* b3 = (const float*)d_in[9];
    float* out = (float*)d_out;

    const int n = in_sizes[0] / 2;            // points
    const int batches = n / 64;               // 64-pt batches (exact for N=2M)
    const int waves = batches / NB;           // waves needed
    const int blocks = waves / 4;             // 4 waves per block

    mlp_mfma_kernel<<<blocks, NTHREADS, 0, stream>>>(
        pos, dir, pos_grid, dir_grid, W1, b1, W2, b2, W3, b3, out);
}

// Round 4
// 186.656 us; speedup vs baseline: 1.7534x; 1.2116x over previous
//
#include <hip/hip_runtime.h>
#include <hip/hip_bf16.h>
#include <math.h>

// R4 = R3 with the pk2 portability fix (ROCm has no __floats2bfloat162_rn).
// Barrier-free MFMA pipeline, wave-private LDS, transposed orientation:
//   layer1: D1[f][p] = W1_frag(A, regs) x feat_frag(B, built via ds_bpermute)
//   transpose D1 (C-layout) -> LDS[p][f] (wave-private, s_waitcnt lgkmcnt only)
//   layer2: D2[n2][p] = W2_frag(A, regs) x h_frag(B, ds_read_b128), acc init = b2
//   epilogue: leaky, dot w3 (per-lane 16 n2), shfl_xor(16,32) over q, sigmoid,
//             coalesced store (lane (c,q) emits point q*16+c).

#define NTHREADS 256
#define NB 4                 // 64-point batches per wave
#define LSTRIDE 72           // shorts per LDS row (144 B, 16B-aligned, low-conflict)
#define WAVE_LDS (64 * LSTRIDE)  // 4608 shorts = 9216 B per wave

typedef __attribute__((ext_vector_type(8))) short bf16x8;
typedef __attribute__((ext_vector_type(4))) float f32x4;
typedef __attribute__((ext_vector_type(4))) int i32x4;
typedef __attribute__((ext_vector_type(2))) int i32x2;

static __device__ __forceinline__ short f2bf(float f) {
    return __builtin_bit_cast(short, __float2bfloat16(f));  // RNE
}
static __device__ __forceinline__ int pk2(float lo, float hi) {
    unsigned short l = (unsigned short)f2bf(lo);
    unsigned short h = (unsigned short)f2bf(hi);
    return (int)(((unsigned int)h << 16) | (unsigned int)l);
}
static __device__ __forceinline__ void wave_lds_fence() {
    __asm__ __volatile__("s_waitcnt lgkmcnt(0)" ::: "memory");
}

static __device__ __forceinline__ void bilerp3(const float* __restrict__ g,
                                               float px, float py, float* f) {
    float fx = px * 255.0f;
    float fy = py * 255.0f;
    int x0 = (int)fx;            // trunc, fx >= 0
    int y0 = (int)fy;
    float xf = fx - floorf(fx);  // jnp.mod(fx, 1.0), fx >= 0
    float yf = fy - floorf(fy);
    int x1 = min(x0 + 1, 255);
    int y1 = min(y0 + 1, 255);
    const float* r00 = g + (y0 * 256 + x0) * 3;
    const float* r01 = g + (y0 * 256 + x1) * 3;
    const float* r10 = g + (y1 * 256 + x0) * 3;
    const float* r11 = g + (y1 * 256 + x1) * 3;
#pragma unroll
    for (int ch = 0; ch < 3; ++ch) {
        float tl = r00[ch], tr = r01[ch], bl = r10[ch], br = r11[ch];
        float top = fmaf(xf, tr - tl, tl);
        float bot = fmaf(xf, br - bl, bl);
        f[ch] = fmaf(yf, bot - top, top);
    }
}

__global__ __launch_bounds__(NTHREADS) void mlp_mfma_kernel(
    const float* __restrict__ pos, const float* __restrict__ dir,
    const float* __restrict__ pos_grid, const float* __restrict__ dir_grid,
    const float* __restrict__ W1, const float* __restrict__ b1,
    const float* __restrict__ W2, const float* __restrict__ b2,
    const float* __restrict__ W3, const float* __restrict__ b3,
    float* __restrict__ out) {
    __shared__ short lds_all[4 * WAVE_LDS];  // 36864 B

    const int w = threadIdx.x >> 6;
    const int lane = threadIdx.x & 63;
    const int c = lane & 15;
    const int q = lane >> 4;

    short* L = lds_all + w * WAVE_LDS;

    // ---- resident weight fragments (transposed orientation: weights are A) ----
    // layer1 A-frag: A[m=f][k]; f = mt*16+c, k = q*8+j. q==0: W1 row + b1 at k=6.
    bf16x8 A1f[4];
#pragma unroll
    for (int mt = 0; mt < 4; ++mt) {
        int f = mt * 16 + c;
        bf16x8 t;
#pragma unroll
        for (int j = 0; j < 8; ++j) {
            float v = 0.0f;
            if (q == 0) {
                if (j < 6) v = W1[f * 6 + j];
                else if (j == 6) v = b1[f];
            }
            t[j] = f2bf(v);
        }
        A1f[mt] = t;
    }
    // layer2 A-frag: A[m=n2][k=f]; n2 = mt*16+c, k = kt*32+q*8+j.
    bf16x8 A2f[2][4];
#pragma unroll
    for (int kt = 0; kt < 2; ++kt)
#pragma unroll
        for (int mt = 0; mt < 4; ++mt) {
            int n2 = mt * 16 + c;
            int k0 = kt * 32 + q * 8;
            bf16x8 t;
#pragma unroll
            for (int j = 0; j < 8; ++j) t[j] = f2bf(W2[n2 * 64 + k0 + j]);
            A2f[kt][mt] = t;
        }
    // epilogue constants: n2 = ft*16 + q*4 + r
    f32x4 ci[4], w3q[4];
#pragma unroll
    for (int ft = 0; ft < 4; ++ft)
#pragma unroll
        for (int r = 0; r < 4; ++r) {
            ci[ft][r] = b2[ft * 16 + q * 4 + r];
            w3q[ft][r] = W3[ft * 16 + q * 4 + r];
        }
    const float b3s = b3[0];

    const long wave_global = (long)blockIdx.x * 4 + w;
    const long base0 = wave_global * (64L * NB);
    const f32x4 zacc = {0.f, 0.f, 0.f, 0.f};

#pragma unroll 1
    for (int ib = 0; ib < NB; ++ib) {
        const long base = base0 + ib * 64;

        // ---- interp: lane = point ----
        float2 pp = ((const float2*)pos)[base + lane];
        float2 dd = ((const float2*)dir)[base + lane];
        float feat[6];
        bilerp3(pos_grid, pp.x, pp.y, feat);
        bilerp3(dir_grid, dd.x, dd.y, feat + 3);
        int d0 = pk2(feat[0], feat[1]);
        int d1 = pk2(feat[2], feat[3]);
        int d2 = pk2(feat[4], feat[5]);
        int d3 = pk2(1.0f, 0.0f);  // bias lane at k=6, zero at k=7

        // ---- layer 1: B-frag via bpermute (source lane = point pt*16+c) ----
        f32x4 acc1[4][4];  // [mt=f-tile][pt]
#pragma unroll
        for (int pt = 0; pt < 4; ++pt) {
            int addr = (pt * 16 + c) << 2;
            i32x4 bi;
            bi[0] = __builtin_amdgcn_ds_bpermute(addr, d0);
            bi[1] = __builtin_amdgcn_ds_bpermute(addr, d1);
            bi[2] = __builtin_amdgcn_ds_bpermute(addr, d2);
            bi[3] = __builtin_amdgcn_ds_bpermute(addr, d3);
            bf16x8 bf = __builtin_bit_cast(bf16x8, bi);
            // q>0 lanes hold garbage, but A1f is 0 there (k>=8) -> contributes 0.
#pragma unroll
            for (int mt = 0; mt < 4; ++mt)
                acc1[mt][pt] = __builtin_amdgcn_mfma_f32_16x16x32_bf16(
                    A1f[mt], bf, zacc, 0, 0, 0);
        }

        // ---- leaky + transpose to LDS[p][f] (wave-private) ----
        wave_lds_fence();  // prior iter's reads complete before overwrite
#pragma unroll
        for (int mt = 0; mt < 4; ++mt)
#pragma unroll
            for (int pt = 0; pt < 4; ++pt) {
                float l0 = acc1[mt][pt][0], l1 = acc1[mt][pt][1];
                float l2 = acc1[mt][pt][2], l3 = acc1[mt][pt][3];
                l0 = fmaxf(l0, 0.01f * l0);
                l1 = fmaxf(l1, 0.01f * l1);
                l2 = fmaxf(l2, 0.01f * l2);
                l3 = fmaxf(l3, 0.01f * l3);
                i32x2 wv;
                wv[0] = pk2(l0, l1);
                wv[1] = pk2(l2, l3);
                // row p = pt*16+c, cols f = mt*16+q*4 .. +3
                *(i32x2*)(L + (pt * 16 + c) * LSTRIDE + mt * 16 + q * 4) = wv;
            }
        wave_lds_fence();  // writes visible to wave before reads

        // ---- layer 2: B-frag from LDS, acc init = b2 ----
        f32x4 acc2[4][4];  // [ft2=n2-tile][pt]
#pragma unroll
        for (int ft = 0; ft < 4; ++ft)
#pragma unroll
            for (int pt = 0; pt < 4; ++pt) acc2[ft][pt] = ci[ft];
#pragma unroll
        for (int kt = 0; kt < 2; ++kt)
#pragma unroll
            for (int pt = 0; pt < 4; ++pt) {
                bf16x8 bf = *(const bf16x8*)(L + (pt * 16 + c) * LSTRIDE +
                                             kt * 32 + q * 8);
#pragma unroll
                for (int ft = 0; ft < 4; ++ft)
                    acc2[ft][pt] = __builtin_amdgcn_mfma_f32_16x16x32_bf16(
                        A2f[kt][ft], bf, acc2[ft][pt], 0, 0, 0);
            }

        // ---- epilogue: leaky, dot w3, reduce over q, sigmoid, store ----
        float s[4];
#pragma unroll
        for (int pt = 0; pt < 4; ++pt) {
            float t = 0.0f;
#pragma unroll
            for (int ft = 0; ft < 4; ++ft)
#pragma unroll
                for (int r = 0; r < 4; ++r) {
                    float x = acc2[ft][pt][r];
                    x = fmaxf(x, 0.01f * x);
                    t = fmaf(x, w3q[ft][r], t);
                }
            t += __shfl_xor(t, 16, 64);
            t += __shfl_xor(t, 32, 64);
            s[pt] = t;
        }
        // lane (c,q) emits point p = q*16 + c with value s[q]
        float sa = (q & 1) ? s[1] : s[0];
        float sb = (q & 1) ? s[3] : s[2];
        float v = (q & 2) ? sb : sa;
        v += b3s;
        v = 1.0f / (1.0f + __expf(-v));
        out[base + q * 16 + c] = v;
    }
}

extern "C" void kernel_launch(void* const* d_in, const int* in_sizes, int n_in,
                              void* d_out, int out_size, void* d_ws,
                              size_t ws_size, hipStream_t stream) {
    const float* pos = (const float*)d_in[0];
    const float* dir = (const float*)d_in[1];
    const float* pos_grid = (const float*)d_in[2];
    const float* dir_grid = (const float*)d_in[3];
    const float* W1 = (const float*)d_in[4];
    const float* b1 = (const float*)d_in[5];
    const float* W2 = (const float*)d_in[6];
    const float* b2 = (const float*)d_in[7];
    const float* W3 = (const float*)d_in[8];
    const float* b3 = (const float*)d_in[9];
    float* out = (float*)d_out;

    const int n = in_sizes[0] / 2;   // points
    const int batches = n / 64;      // 32768 for N=2M
    const int waves = batches / NB;  // 8192
    const int blocks = waves / 4;    // 2048

    mlp_mfma_kernel<<<blocks, NTHREADS, 0, stream>>>(
        pos, dir, pos_grid, dir_grid, W1, b1, W2, b2, W3, b3, out);
}

// Round 5
// 158.743 us; speedup vs baseline: 2.0618x; 1.1758x over previous
//
#include <hip/hip_runtime.h>
#include <hip/hip_bf16.h>
#include <math.h>

// R5: per-pt pipeline to cut live accumulator registers (2 -> 3 waves/SIMD).
//   For each 16-point tile: layer1 MFMA (acc[4]) -> leaky/pack -> LDS transpose
//   -> read B-frag -> layer2 MFMA (acc[4]) -> epilogue partial. Only one tile's
//   accumulators live at any time. Barrier-free, wave-private LDS, weights
//   resident as A-fragments. pos/dir software-prefetched one batch ahead.

#define NTHREADS 256
#define NB 4                 // 64-point batches per wave
#define LSTRIDE 72           // shorts per LDS row (144 B, 16B-aligned)
#define WAVE_LDS (64 * LSTRIDE)  // 9216 B per wave

typedef __attribute__((ext_vector_type(8))) short bf16x8;
typedef __attribute__((ext_vector_type(4))) float f32x4;
typedef __attribute__((ext_vector_type(4))) int i32x4;
typedef __attribute__((ext_vector_type(2))) int i32x2;

static __device__ __forceinline__ short f2bf(float f) {
    return __builtin_bit_cast(short, __float2bfloat16(f));  // RNE
}
static __device__ __forceinline__ int pk2(float lo, float hi) {
    unsigned short l = (unsigned short)f2bf(lo);
    unsigned short h = (unsigned short)f2bf(hi);
    return (int)(((unsigned int)h << 16) | (unsigned int)l);
}

static __device__ __forceinline__ void bilerp3(const float* __restrict__ g,
                                               float px, float py, float* f) {
    float fx = px * 255.0f;
    float fy = py * 255.0f;
    int x0 = (int)fx;            // trunc, fx >= 0
    int y0 = (int)fy;
    float xf = fx - floorf(fx);  // jnp.mod(fx, 1.0), fx >= 0
    float yf = fy - floorf(fy);
    int x1 = min(x0 + 1, 255);
    int y1 = min(y0 + 1, 255);
    const float* r00 = g + (y0 * 256 + x0) * 3;
    const float* r01 = g + (y0 * 256 + x1) * 3;
    const float* r10 = g + (y1 * 256 + x0) * 3;
    const float* r11 = g + (y1 * 256 + x1) * 3;
#pragma unroll
    for (int ch = 0; ch < 3; ++ch) {
        float tl = r00[ch], tr = r01[ch], bl = r10[ch], br = r11[ch];
        float top = fmaf(xf, tr - tl, tl);
        float bot = fmaf(xf, br - bl, bl);
        f[ch] = fmaf(yf, bot - top, top);
    }
}

__global__ __launch_bounds__(NTHREADS, 3) void mlp_mfma_kernel(
    const float* __restrict__ pos, const float* __restrict__ dir,
    const float* __restrict__ pos_grid, const float* __restrict__ dir_grid,
    const float* __restrict__ W1, const float* __restrict__ b1,
    const float* __restrict__ W2, const float* __restrict__ b2,
    const float* __restrict__ W3, const float* __restrict__ b3,
    float* __restrict__ out) {
    __shared__ short lds_all[4 * WAVE_LDS];  // 36864 B

    const int w = threadIdx.x >> 6;
    const int lane = threadIdx.x & 63;
    const int c = lane & 15;
    const int q = lane >> 4;

    short* L = lds_all + w * WAVE_LDS;

    // ---- resident weight fragments (weights are the MFMA A operand) ----
    // layer1 A-frag: A[m=f][k]; f = mt*16+c, k = q*8+j. q==0: W1 row + b1 at k=6.
    bf16x8 A1f[4];
#pragma unroll
    for (int mt = 0; mt < 4; ++mt) {
        int f = mt * 16 + c;
        bf16x8 t;
#pragma unroll
        for (int j = 0; j < 8; ++j) {
            float v = 0.0f;
            if (q == 0) {
                if (j < 6) v = W1[f * 6 + j];
                else if (j == 6) v = b1[f];
            }
            t[j] = f2bf(v);
        }
        A1f[mt] = t;
    }
    // layer2 A-frag: A[m=n2][k=f]; n2 = mt*16+c, k = kt*32+q*8+j.
    bf16x8 A2f[2][4];
#pragma unroll
    for (int kt = 0; kt < 2; ++kt)
#pragma unroll
        for (int mt = 0; mt < 4; ++mt) {
            int n2 = mt * 16 + c;
            int k0 = kt * 32 + q * 8;
            bf16x8 t;
#pragma unroll
            for (int j = 0; j < 8; ++j) t[j] = f2bf(W2[n2 * 64 + k0 + j]);
            A2f[kt][mt] = t;
        }
    // epilogue constants: n2 = ft*16 + q*4 + r
    f32x4 ci[4], w3q[4];
#pragma unroll
    for (int ft = 0; ft < 4; ++ft)
#pragma unroll
        for (int r = 0; r < 4; ++r) {
            ci[ft][r] = b2[ft * 16 + q * 4 + r];
            w3q[ft][r] = W3[ft * 16 + q * 4 + r];
        }
    const float b3s = b3[0];

    const long wave_global = (long)blockIdx.x * 4 + w;
    const long base0 = wave_global * (64L * NB);
    const f32x4 zacc = {0.f, 0.f, 0.f, 0.f};

    // prefetched point coords (lane = point)
    float2 pp = ((const float2*)pos)[base0 + lane];
    float2 dd = ((const float2*)dir)[base0 + lane];

#pragma unroll 1
    for (int ib = 0; ib < NB; ++ib) {
        const long base = base0 + ib * 64;
        // prefetch next batch (clamped in-range; last iter reloads current)
        const long nbase = (ib + 1 < NB) ? (base + 64) : base;
        float2 ppn = ((const float2*)pos)[nbase + lane];
        float2 ddn = ((const float2*)dir)[nbase + lane];

        // ---- interp: lane = point ----
        float feat[6];
        bilerp3(pos_grid, pp.x, pp.y, feat);
        bilerp3(dir_grid, dd.x, dd.y, feat + 3);
        int d0 = pk2(feat[0], feat[1]);
        int d1 = pk2(feat[2], feat[3]);
        int d2 = pk2(feat[4], feat[5]);
        int d3 = pk2(1.0f, 0.0f);  // bias at k=6, zero at k=7

        float s[4];
#pragma unroll
        for (int pt = 0; pt < 4; ++pt) {
            const int row = pt * 16 + c;
            // layer-1 B-frag via bpermute (source lane = point row)
            const int addr = row << 2;
            i32x4 bi;
            bi[0] = __builtin_amdgcn_ds_bpermute(addr, d0);
            bi[1] = __builtin_amdgcn_ds_bpermute(addr, d1);
            bi[2] = __builtin_amdgcn_ds_bpermute(addr, d2);
            bi[3] = __builtin_amdgcn_ds_bpermute(addr, d3);
            bf16x8 bfrag = __builtin_bit_cast(bf16x8, bi);
            // q>0 lanes carry replicated junk at k>=8; A1f is zero there.

            // layer 1: 4 MFMAs, acc lives only within this pt
            f32x4 a1[4];
#pragma unroll
            for (int mt = 0; mt < 4; ++mt)
                a1[mt] = __builtin_amdgcn_mfma_f32_16x16x32_bf16(
                    A1f[mt], bfrag, zacc, 0, 0, 0);

            // leaky + pack + transpose this tile: row p, cols f
#pragma unroll
            for (int mt = 0; mt < 4; ++mt) {
                float l0 = a1[mt][0], l1 = a1[mt][1];
                float l2 = a1[mt][2], l3 = a1[mt][3];
                l0 = fmaxf(l0, 0.01f * l0);
                l1 = fmaxf(l1, 0.01f * l1);
                l2 = fmaxf(l2, 0.01f * l2);
                l3 = fmaxf(l3, 0.01f * l3);
                i32x2 wv;
                wv[0] = pk2(l0, l1);
                wv[1] = pk2(l2, l3);
                *(i32x2*)(L + row * LSTRIDE + mt * 16 + q * 4) = wv;
            }

            // layer 2 B-frag for this tile (DS is in-order per wave; compiler
            // inserts the lgkmcnt waits for the RAW)
            bf16x8 h0 = *(const bf16x8*)(L + row * LSTRIDE + q * 8);
            bf16x8 h1 = *(const bf16x8*)(L + row * LSTRIDE + 32 + q * 8);

            f32x4 a2[4];
#pragma unroll
            for (int ft = 0; ft < 4; ++ft) a2[ft] = ci[ft];
#pragma unroll
            for (int ft = 0; ft < 4; ++ft) {
                a2[ft] = __builtin_amdgcn_mfma_f32_16x16x32_bf16(
                    A2f[0][ft], h0, a2[ft], 0, 0, 0);
                a2[ft] = __builtin_amdgcn_mfma_f32_16x16x32_bf16(
                    A2f[1][ft], h1, a2[ft], 0, 0, 0);
            }

            // epilogue partial: leaky, dot w3, reduce over q
            float t = 0.0f;
#pragma unroll
            for (int ft = 0; ft < 4; ++ft)
#pragma unroll
                for (int r = 0; r < 4; ++r) {
                    float x = a2[ft][r];
                    x = fmaxf(x, 0.01f * x);
                    t = fmaf(x, w3q[ft][r], t);
                }
            t += __shfl_xor(t, 16, 64);
            t += __shfl_xor(t, 32, 64);
            s[pt] = t;
        }

        // lane (c,q) emits point p = q*16 + c with value s[q]
        float sa = (q & 1) ? s[1] : s[0];
        float sb = (q & 1) ? s[3] : s[2];
        float v = (q & 2) ? sb : sa;
        v += b3s;
        v = 1.0f / (1.0f + __expf(-v));
        out[base + q * 16 + c] = v;

        pp = ppn;
        dd = ddn;
    }
}

extern "C" void kernel_launch(void* const* d_in, const int* in_sizes, int n_in,
                              void* d_out, int out_size, void* d_ws,
                              size_t ws_size, hipStream_t stream) {
    const float* pos = (const float*)d_in[0];
    const float* dir = (const float*)d_in[1];
    const float* pos_grid = (const float*)d_in[2];
    const float* dir_grid = (const float*)d_in[3];
    const float* W1 = (const float*)d_in[4];
    const float* b1 = (const float*)d_in[5];
    const float* W2 = (const float*)d_in[6];
    const float* b2 = (const float*)d_in[7];
    const float* W3 = (const float*)d_in[8];
    const float* b3 = (const float*)d_in[9];
    float* out = (float*)d_out;

    const int n = in_sizes[0] / 2;   // points
    const int batches = n / 64;      // 32768 for N=2M
    const int waves = batches / NB;  // 8192
    const int blocks = waves / 4;    // 2048

    mlp_mfma_kernel<<<blocks, NTHREADS, 0, stream>>>(
        pos, dir, pos_grid, dir_grid, W1, b1, W2, b2, W3, b3, out);
}